// Round 3
// baseline (946.735 us; speedup 1.0000x reference)
//
#include <hip/hip_runtime.h>
#include <hip/hip_bf16.h>

#define LDIM 4096
#define FDIM 64
#define BM 64
#define BK 256
#define NIT (LDIM / BK)   // 16
#define SAP 264           // sA/sH row stride in bf16 elems (256 + 8 pad)
#define STP 72            // sT row stride in bf16 elems (64 + 8 pad)

typedef __attribute__((ext_vector_type(8))) __bf16 bf16x8;
typedef __attribute__((ext_vector_type(4))) float f32x4;

__device__ __forceinline__ unsigned short f2bf(float f) {
    unsigned int u = __float_as_uint(f);
    u += 0x7fffu + ((u >> 16) & 1u);       // round-to-nearest-even
    return (unsigned short)(u >> 16);
}

// Fully fused: out[b] = adj[b] @ (text[b] @ W) + bias.  NO workspace.
// Each block (b, mb) owns out rows [m0, m0+64). Per K-tile of 256:
//   phase 1: text[k-tile] (fp32, L2-resident) -> bf16 -> sT
//   phase 2: hidden tile = sT @ wB via MFMA (redundant across the 64 blocks of a batch;
//            total extra MFMA == main gemm's own MFMA count -> ~8 us chip-wide)
//   phase 3: adj tile -> bf16 -> sA (reusing sT's LDS space); hidden acc -> bf16 -> sH
//   phase 4: main MFMA acc += sA @ sH
// LDS: max(sT 36.9K, sA 33.8K) + sH 33.8K = 70.7 KB -> 2 blocks/CU.
__global__ __launch_bounds__(256, 2) void fused_kernel(
    const float* __restrict__ text, const float* __restrict__ adj,
    const float* __restrict__ weight, const float* __restrict__ bias,
    float* __restrict__ out)
{
    const int b  = blockIdx.x & 7;         // batch -> XCD affinity (text[b] L2-resident)
    const int mb = blockIdx.x >> 3;        // 0..63
    const int m0 = mb * BM;
    const int tid  = threadIdx.x;
    const int w    = tid >> 6;
    const int lane = tid & 63;
    const int fm = lane & 15;
    const int fq = lane >> 4;

    __shared__ __align__(16) unsigned short sTA[256 * STP]; // sT[256][72] UNION sA[64][264]
    __shared__ __align__(16) unsigned short sH[64 * SAP];   // hidden tile as B: [n=o][k]

    const float* tbase = text + (size_t)b * LDIM * FDIM;
    const float* abase = adj  + ((size_t)b * LDIM + m0) * LDIM;

    // W B-fragments, gathered once, held in 32 VGPRs for the whole kernel.
    // wB[fs][ob] elem j = W[f][o] with f = fs*32 + fq*8 + j, o = ob*16 + fm.
    bf16x8 wB[2][4];
    #pragma unroll
    for (int fs = 0; fs < 2; ++fs)
        #pragma unroll
        for (int ob = 0; ob < 4; ++ob) {
            union { unsigned short us[8]; bf16x8 v; } u8;
            #pragma unroll
            for (int j = 0; j < 8; ++j)
                u8.us[j] = f2bf(weight[(size_t)(fs * 32 + fq * 8 + j) * FDIM + ob * 16 + fm]);
            wB[fs][ob] = u8.v;
        }

    // Register staging. text tile: 256 rows x 64 f32 = 4096 float4; idx = i*256+tid:
    //   row = idx>>4 (16 float4/row), col4 = idx&15. 1 KB contiguous per wave-instr.
    // adj tile: 64 rows x 256 f32; row = idx>>6, col4 = idx&63. 1 KB contiguous/row.
    float4 tReg[16]; float4 aReg[16];
    #pragma unroll
    for (int i = 0; i < 16; ++i) {
        int idx = i * 256 + tid;
        tReg[i] = *(const float4*)(tbase + (size_t)(idx >> 4) * FDIM + (idx & 15) * 4);
    }
    #pragma unroll
    for (int i = 0; i < 16; ++i) {
        int idx = i * 256 + tid;
        aReg[i] = *(const float4*)(abase + (size_t)(idx >> 6) * LDIM + (idx & 63) * 4);
    }

    f32x4 acc[4];
    #pragma unroll
    for (int nf = 0; nf < 4; ++nf) acc[nf] = (f32x4){0.f, 0.f, 0.f, 0.f};

    for (int it = 0; it < NIT; ++it) {
        const bool more = (it + 1 < NIT);
        const int  k0n  = (it + 1) * BK;

        __syncthreads();                   // b1: prev main-MFMA reads of sA/sH done
        // phase 1: text -> sT (bf16)
        #pragma unroll
        for (int i = 0; i < 16; ++i) {
            int idx = i * 256 + tid;
            union { unsigned short us[4]; uint2 v; } pk;
            pk.us[0] = f2bf(tReg[i].x); pk.us[1] = f2bf(tReg[i].y);
            pk.us[2] = f2bf(tReg[i].z); pk.us[3] = f2bf(tReg[i].w);
            *(uint2*)&sTA[(idx >> 4) * STP + (idx & 15) * 4] = pk.v;
        }
        __syncthreads();                   // b2

        // prefetch next text tile (L2-resident; consumed next phase 1)
        if (more) {
            #pragma unroll
            for (int i = 0; i < 16; ++i) {
                int idx = i * 256 + tid;
                tReg[i] = *(const float4*)(tbase + (size_t)(k0n + (idx >> 4)) * FDIM + (idx & 15) * 4);
            }
        }

        // phase 2: hidden tile MFMA. Wave w computes k-rows [w*64, w*64+64).
        f32x4 acc2[4][4];
        #pragma unroll
        for (int i = 0; i < 4; ++i)
            #pragma unroll
            for (int ob = 0; ob < 4; ++ob) acc2[i][ob] = (f32x4){0.f, 0.f, 0.f, 0.f};
        #pragma unroll
        for (int fs = 0; fs < 2; ++fs)
            #pragma unroll
            for (int i = 0; i < 4; ++i) {
                bf16x8 af = *(const bf16x8*)&sTA[(w * 64 + i * 16 + fm) * STP + fs * 32 + fq * 8];
                #pragma unroll
                for (int ob = 0; ob < 4; ++ob)
                    acc2[i][ob] = __builtin_amdgcn_mfma_f32_16x16x32_bf16(af, wB[fs][ob], acc2[i][ob], 0, 0, 0);
            }
        __syncthreads();                   // b3: sT reads done -> region free for sA

        // phase 3: adj -> sA (bf16); hidden acc -> sH (bf16, [n][k])
        #pragma unroll
        for (int i = 0; i < 16; ++i) {
            int idx = i * 256 + tid;
            union { unsigned short us[4]; uint2 v; } pk;
            pk.us[0] = f2bf(aReg[i].x); pk.us[1] = f2bf(aReg[i].y);
            pk.us[2] = f2bf(aReg[i].z); pk.us[3] = f2bf(aReg[i].w);
            *(uint2*)&sTA[(idx >> 6) * SAP + (idx & 63) * 4] = pk.v;
        }
        // C/D layout: col(=o within 16) = fm, row(=k within 16) = fq*4 + r
        #pragma unroll
        for (int i = 0; i < 4; ++i)
            #pragma unroll
            for (int ob = 0; ob < 4; ++ob) {
                union { unsigned short us[4]; uint2 v; } pk;
                pk.us[0] = f2bf(acc2[i][ob][0]); pk.us[1] = f2bf(acc2[i][ob][1]);
                pk.us[2] = f2bf(acc2[i][ob][2]); pk.us[3] = f2bf(acc2[i][ob][3]);
                *(uint2*)&sH[(ob * 16 + fm) * SAP + w * 64 + i * 16 + fq * 4] = pk.v;
            }
        // prefetch next adj tile (HBM; consumed next phase 3 -> ~full cycle of cover)
        if (more) {
            #pragma unroll
            for (int i = 0; i < 16; ++i) {
                int idx = i * 256 + tid;
                aReg[i] = *(const float4*)(abase + (size_t)(idx >> 6) * LDIM + k0n + (idx & 63) * 4);
            }
        }
        __syncthreads();                   // b4

        // phase 4: main MFMA. Wave w: 16 M-rows x 64 N, K=256.
        #pragma unroll
        for (int kf = 0; kf < 8; ++kf) {
            bf16x8 af = *(const bf16x8*)&sTA[(w * 16 + fm) * SAP + kf * 32 + fq * 8];
            #pragma unroll
            for (int nf = 0; nf < 4; ++nf) {
                bf16x8 bfr = *(const bf16x8*)&sH[(nf * 16 + fm) * SAP + kf * 32 + fq * 8];
                acc[nf] = __builtin_amdgcn_mfma_f32_16x16x32_bf16(af, bfr, acc[nf], 0, 0, 0);
            }
        }
    }

    // epilogue: C/D layout col = lane&15, row = (lane>>4)*4 + reg
    float* obase = out + ((size_t)b * LDIM + m0 + w * 16 + fq * 4) * FDIM + fm;
    #pragma unroll
    for (int nf = 0; nf < 4; ++nf) {
        float bv = bias[nf * 16 + fm];
        #pragma unroll
        for (int r = 0; r < 4; ++r)
            obase[(size_t)r * FDIM + nf * 16] = acc[nf][r] + bv;
    }
}

extern "C" void kernel_launch(void* const* d_in, const int* in_sizes, int n_in,
                              void* d_out, int out_size, void* d_ws, size_t ws_size,
                              hipStream_t stream) {
    const float* text   = (const float*)d_in[0];
    const float* adj    = (const float*)d_in[1];
    const float* weight = (const float*)d_in[2];
    const float* bias   = (const float*)d_in[3];
    float* out = (float*)d_out;
    (void)d_ws; (void)ws_size;             // workspace intentionally unused

    fused_kernel<<<512, 256, 0, stream>>>(text, adj, weight, bias, out);
}

// Round 4
// 719.554 us; speedup vs baseline: 1.3157x; 1.3157x over previous
//
#include <hip/hip_runtime.h>
#include <hip/hip_bf16.h>

#define LDIM 4096
#define FDIM 64
#define BM 64
#define BK 256
#define NIT (LDIM / BK)   // 16
#define SAP 264           // sA/sH row stride in bf16 elems (256 + 8 pad)
#define STP 72            // sT row stride in bf16 elems (64 + 8 pad)

typedef __attribute__((ext_vector_type(8))) __bf16 bf16x8;
typedef __attribute__((ext_vector_type(4))) float f32x4;

__device__ __forceinline__ unsigned short f2bf(float f) {
    unsigned int u = __float_as_uint(f);
    u += 0x7fffu + ((u >> 16) & 1u);       // round-to-nearest-even
    return (unsigned short)(u >> 16);
}

// Fully fused: out[b] = adj[b] @ (text[b] @ W) + bias.  NO workspace (ws poison
// costs ~156 us of harness fills; measured harness floor without ws ~= 522 us).
// Each block (b, mb) owns out rows [m0, m0+64). Per K-tile of 256:
//   phase 1: text[k-tile] (fp32, L2-resident on this batch's XCD) -> bf16 -> sT
//   phase 2: hidden tile = sT @ wB via MFMA, converted+stored to sH PER k-ROW-GROUP
//            (incremental acc2: 16 live regs instead of 64 -> no spill at ~200 VGPR)
//   phase 3: adj tile (reg-prefetched a full cycle ago) -> bf16 -> sA (reuses sT space)
//   phase 4: main MFMA acc += sA @ sH
// LDS: max(sT 36.9K, sA 33.8K) + sH 33.8K = 70.7 KB -> 2 blocks/CU (needs <=256 VGPR,
// hence __launch_bounds__(256) WITHOUT a min-waves arg: the (256,2) form capped the
// allocator at 128 VGPR and produced 292 MB of scratch writes in round 3).
__global__ __launch_bounds__(256) void fused_kernel(
    const float* __restrict__ text, const float* __restrict__ adj,
    const float* __restrict__ weight, const float* __restrict__ bias,
    float* __restrict__ out)
{
    const int b  = blockIdx.x & 7;         // batch -> XCD affinity (text[b] L2-resident)
    const int mb = blockIdx.x >> 3;        // 0..63
    const int m0 = mb * BM;
    const int tid  = threadIdx.x;
    const int w    = tid >> 6;
    const int lane = tid & 63;
    const int fm = lane & 15;
    const int fq = lane >> 4;

    __shared__ __align__(16) unsigned short sTA[256 * STP]; // sT[256][72] UNION sA[64][264]
    __shared__ __align__(16) unsigned short sH[64 * SAP];   // hidden tile as B: [n=o][k]

    const float* tbase = text + (size_t)b * LDIM * FDIM;
    const float* abase = adj  + ((size_t)b * LDIM + m0) * LDIM;

    // W B-fragments, gathered once, held in 32 VGPRs for the whole kernel.
    // wB[fs][ob] elem j = W[f][o] with f = fs*32 + fq*8 + j, o = ob*16 + fm.
    bf16x8 wB[2][4];
    #pragma unroll
    for (int fs = 0; fs < 2; ++fs)
        #pragma unroll
        for (int ob = 0; ob < 4; ++ob) {
            union { unsigned short us[8]; bf16x8 v; } u8;
            #pragma unroll
            for (int j = 0; j < 8; ++j)
                u8.us[j] = f2bf(weight[(size_t)(fs * 32 + fq * 8 + j) * FDIM + ob * 16 + fm]);
            wB[fs][ob] = u8.v;
        }

    // Register staging. text tile: 256 rows x 64 f32 = 4096 float4; idx = i*256+tid:
    //   row = idx>>4 (16 float4/row), col4 = idx&15. 1 KB contiguous per wave-instr.
    // adj tile: 64 rows x 256 f32; row = idx>>6, col4 = idx&63. 1 KB contiguous/row.
    float4 tReg[16]; float4 aReg[16];
    #pragma unroll
    for (int i = 0; i < 16; ++i) {
        int idx = i * 256 + tid;
        tReg[i] = *(const float4*)(tbase + (size_t)(idx >> 4) * FDIM + (idx & 15) * 4);
    }
    #pragma unroll
    for (int i = 0; i < 16; ++i) {
        int idx = i * 256 + tid;
        aReg[i] = *(const float4*)(abase + (size_t)(idx >> 6) * LDIM + (idx & 63) * 4);
    }

    f32x4 acc[4];
    #pragma unroll
    for (int nf = 0; nf < 4; ++nf) acc[nf] = (f32x4){0.f, 0.f, 0.f, 0.f};

    for (int it = 0; it < NIT; ++it) {
        const bool more = (it + 1 < NIT);
        const int  k0n  = (it + 1) * BK;

        __syncthreads();                   // b1: prev main-MFMA reads of sA/sH done
        // phase 1: text -> sT (bf16)
        #pragma unroll
        for (int i = 0; i < 16; ++i) {
            int idx = i * 256 + tid;
            union { unsigned short us[4]; uint2 v; } pk;
            pk.us[0] = f2bf(tReg[i].x); pk.us[1] = f2bf(tReg[i].y);
            pk.us[2] = f2bf(tReg[i].z); pk.us[3] = f2bf(tReg[i].w);
            *(uint2*)&sTA[(idx >> 4) * STP + (idx & 15) * 4] = pk.v;
        }
        __syncthreads();                   // b2

        // prefetch next text tile (L2-resident; consumed next phase 1)
        if (more) {
            #pragma unroll
            for (int i = 0; i < 16; ++i) {
                int idx = i * 256 + tid;
                tReg[i] = *(const float4*)(tbase + (size_t)(k0n + (idx >> 4)) * FDIM + (idx & 15) * 4);
            }
        }

        // phase 2: hidden tile MFMA, INCREMENTAL per k-row-group i.
        // Wave w computes k-rows [w*64, w*64+64); each i: 16 k-rows x 64 o.
        // Store to sH immediately (prev phase-4 sH reads finished before b1).
        #pragma unroll
        for (int i = 0; i < 4; ++i) {
            bf16x8 af0 = *(const bf16x8*)&sTA[(w * 64 + i * 16 + fm) * STP + 0 * 32 + fq * 8];
            bf16x8 af1 = *(const bf16x8*)&sTA[(w * 64 + i * 16 + fm) * STP + 1 * 32 + fq * 8];
            #pragma unroll
            for (int ob = 0; ob < 4; ++ob) {
                f32x4 a2 = (f32x4){0.f, 0.f, 0.f, 0.f};
                a2 = __builtin_amdgcn_mfma_f32_16x16x32_bf16(af0, wB[0][ob], a2, 0, 0, 0);
                a2 = __builtin_amdgcn_mfma_f32_16x16x32_bf16(af1, wB[1][ob], a2, 0, 0, 0);
                // C/D layout: col(=o within 16) = fm, row(=k within 16) = fq*4 + r
                union { unsigned short us[4]; uint2 v; } pk;
                pk.us[0] = f2bf(a2[0]); pk.us[1] = f2bf(a2[1]);
                pk.us[2] = f2bf(a2[2]); pk.us[3] = f2bf(a2[3]);
                *(uint2*)&sH[(ob * 16 + fm) * SAP + w * 64 + i * 16 + fq * 4] = pk.v;
            }
        }
        __syncthreads();                   // b3: sT reads done -> region free for sA

        // phase 3: adj -> sA (bf16) from the prefetch issued LAST iteration
        #pragma unroll
        for (int i = 0; i < 16; ++i) {
            int idx = i * 256 + tid;
            union { unsigned short us[4]; uint2 v; } pk;
            pk.us[0] = f2bf(aReg[i].x); pk.us[1] = f2bf(aReg[i].y);
            pk.us[2] = f2bf(aReg[i].z); pk.us[3] = f2bf(aReg[i].w);
            *(uint2*)&sTA[(idx >> 6) * SAP + (idx & 63) * 4] = pk.v;
        }
        // prefetch next adj tile (HBM; consumed next phase 3 -> ~full cycle of cover)
        if (more) {
            #pragma unroll
            for (int i = 0; i < 16; ++i) {
                int idx = i * 256 + tid;
                aReg[i] = *(const float4*)(abase + (size_t)(idx >> 6) * LDIM + k0n + (idx & 63) * 4);
            }
        }
        __syncthreads();                   // b4

        // phase 4: main MFMA. Wave w: 16 M-rows x 64 N, K=256.
        #pragma unroll
        for (int kf = 0; kf < 8; ++kf) {
            bf16x8 af = *(const bf16x8*)&sTA[(w * 16 + fm) * SAP + kf * 32 + fq * 8];
            #pragma unroll
            for (int nf = 0; nf < 4; ++nf) {
                bf16x8 bfr = *(const bf16x8*)&sH[(nf * 16 + fm) * SAP + kf * 32 + fq * 8];
                acc[nf] = __builtin_amdgcn_mfma_f32_16x16x32_bf16(af, bfr, acc[nf], 0, 0, 0);
            }
        }
    }

    // epilogue: C/D layout col = lane&15, row = (lane>>4)*4 + reg
    float* obase = out + ((size_t)b * LDIM + m0 + w * 16 + fq * 4) * FDIM + fm;
    #pragma unroll
    for (int nf = 0; nf < 4; ++nf) {
        float bv = bias[nf * 16 + fm];
        #pragma unroll
        for (int r = 0; r < 4; ++r)
            obase[(size_t)r * FDIM + nf * 16] = acc[nf][r] + bv;
    }
}

extern "C" void kernel_launch(void* const* d_in, const int* in_sizes, int n_in,
                              void* d_out, int out_size, void* d_ws, size_t ws_size,
                              hipStream_t stream) {
    const float* text   = (const float*)d_in[0];
    const float* adj    = (const float*)d_in[1];
    const float* weight = (const float*)d_in[2];
    const float* bias   = (const float*)d_in[3];
    float* out = (float*)d_out;
    (void)d_ws; (void)ws_size;             // workspace intentionally unused

    fused_kernel<<<512, 256, 0, stream>>>(text, adj, weight, bias, out);
}

// Round 5
// 705.641 us; speedup vs baseline: 1.3417x; 1.0197x over previous
//
#include <hip/hip_runtime.h>
#include <hip/hip_bf16.h>

#define LDIM 4096
#define FDIM 64
#define BM 64
#define BK 256
#define NIT (LDIM / BK)   // 16
#define SAP 264           // sA/sH row stride in bf16 elems (256 + 8 pad)
#define STP 72            // sT row stride in bf16 elems (64 + 8 pad)

typedef __attribute__((ext_vector_type(8))) __bf16 bf16x8;
typedef __attribute__((ext_vector_type(4))) float f32x4;

__device__ __forceinline__ unsigned short f2bf(float f) {
    unsigned int u = __float_as_uint(f);
    u += 0x7fffu + ((u >> 16) & 1u);       // round-to-nearest-even
    return (unsigned short)(u >> 16);
}

// Fully fused: out[b] = adj[b] @ (text[b] @ W) + bias.  NO workspace.
// K-PHASE STAGGER (this round's change): adj rows are 16 KB apart, so a k-tile's
// 64 row-chunks alias onto the same HBM channel subset; with all blocks walking
// k-tiles in the same order from a synchronized launch, the whole chip hammers
// one channel subset at a time (effective ~2.7 TB/s, structure-insensitive —
// explains the r0/r2/r4 nulls). Rotating each block's k-tile order by
// phase = mb & 15 spreads concurrent blocks across all 16 k-phases -> all
// channels stay busy. Accumulation order per block changes; fp32 acc, tolerance ok.
__global__ __launch_bounds__(256) void fused_kernel(
    const float* __restrict__ text, const float* __restrict__ adj,
    const float* __restrict__ weight, const float* __restrict__ bias,
    float* __restrict__ out)
{
    const int b  = blockIdx.x & 7;         // batch -> XCD affinity (text[b] L2-resident)
    const int mb = blockIdx.x >> 3;        // 0..63
    const int m0 = mb * BM;
    const int phase = mb & 15;             // k-tile rotation offset
    const int tid  = threadIdx.x;
    const int w    = tid >> 6;
    const int lane = tid & 63;
    const int fm = lane & 15;
    const int fq = lane >> 4;

    __shared__ __align__(16) unsigned short sTA[256 * STP]; // sT[256][72] UNION sA[64][264]
    __shared__ __align__(16) unsigned short sH[64 * SAP];   // hidden tile as B: [n=o][k]

    const float* tbase = text + (size_t)b * LDIM * FDIM;
    const float* abase = adj  + ((size_t)b * LDIM + m0) * LDIM;

    // W B-fragments, gathered once, held in 32 VGPRs for the whole kernel.
    // wB[fs][ob] elem j = W[f][o] with f = fs*32 + fq*8 + j, o = ob*16 + fm.
    bf16x8 wB[2][4];
    #pragma unroll
    for (int fs = 0; fs < 2; ++fs)
        #pragma unroll
        for (int ob = 0; ob < 4; ++ob) {
            union { unsigned short us[8]; bf16x8 v; } u8;
            #pragma unroll
            for (int j = 0; j < 8; ++j)
                u8.us[j] = f2bf(weight[(size_t)(fs * 32 + fq * 8 + j) * FDIM + ob * 16 + fm]);
            wB[fs][ob] = u8.v;
        }

    // Register staging. text tile: 256 rows x 64 f32 = 4096 float4; idx = i*256+tid:
    //   row = idx>>4 (16 float4/row), col4 = idx&15. 1 KB contiguous per wave-instr.
    // adj tile: 64 rows x 256 f32; row = idx>>6, col4 = idx&63. 1 KB contiguous/row.
    float4 tReg[16]; float4 aReg[16];
    {
        const int k0p = phase * BK;        // first tile in rotated order
        #pragma unroll
        for (int i = 0; i < 16; ++i) {
            int idx = i * 256 + tid;
            tReg[i] = *(const float4*)(tbase + (size_t)(k0p + (idx >> 4)) * FDIM + (idx & 15) * 4);
        }
        #pragma unroll
        for (int i = 0; i < 16; ++i) {
            int idx = i * 256 + tid;
            aReg[i] = *(const float4*)(abase + (size_t)(idx >> 6) * LDIM + k0p + (idx & 63) * 4);
        }
    }

    f32x4 acc[4];
    #pragma unroll
    for (int nf = 0; nf < 4; ++nf) acc[nf] = (f32x4){0.f, 0.f, 0.f, 0.f};

    for (int it = 0; it < NIT; ++it) {
        const bool more = (it + 1 < NIT);
        const int  ktn  = (it + 1 + phase) & (NIT - 1);   // next tile in rotated order
        const int  k0n  = ktn * BK;

        __syncthreads();                   // b1: prev main-MFMA reads of sA/sH done
        // phase 1: text -> sT (bf16)
        #pragma unroll
        for (int i = 0; i < 16; ++i) {
            int idx = i * 256 + tid;
            union { unsigned short us[4]; uint2 v; } pk;
            pk.us[0] = f2bf(tReg[i].x); pk.us[1] = f2bf(tReg[i].y);
            pk.us[2] = f2bf(tReg[i].z); pk.us[3] = f2bf(tReg[i].w);
            *(uint2*)&sTA[(idx >> 4) * STP + (idx & 15) * 4] = pk.v;
        }
        __syncthreads();                   // b2

        // prefetch next text tile (L2-resident; consumed next phase 1)
        if (more) {
            #pragma unroll
            for (int i = 0; i < 16; ++i) {
                int idx = i * 256 + tid;
                tReg[i] = *(const float4*)(tbase + (size_t)(k0n + (idx >> 4)) * FDIM + (idx & 15) * 4);
            }
        }

        // phase 2: hidden tile MFMA, INCREMENTAL per k-row-group i.
        // Wave w computes k-rows [w*64, w*64+64); each i: 16 k-rows x 64 o.
        // Store to sH immediately (prev phase-4 sH reads finished before b1).
        #pragma unroll
        for (int i = 0; i < 4; ++i) {
            bf16x8 af0 = *(const bf16x8*)&sTA[(w * 64 + i * 16 + fm) * STP + 0 * 32 + fq * 8];
            bf16x8 af1 = *(const bf16x8*)&sTA[(w * 64 + i * 16 + fm) * STP + 1 * 32 + fq * 8];
            #pragma unroll
            for (int ob = 0; ob < 4; ++ob) {
                f32x4 a2 = (f32x4){0.f, 0.f, 0.f, 0.f};
                a2 = __builtin_amdgcn_mfma_f32_16x16x32_bf16(af0, wB[0][ob], a2, 0, 0, 0);
                a2 = __builtin_amdgcn_mfma_f32_16x16x32_bf16(af1, wB[1][ob], a2, 0, 0, 0);
                // C/D layout: col(=o within 16) = fm, row(=k within 16) = fq*4 + r
                union { unsigned short us[4]; uint2 v; } pk;
                pk.us[0] = f2bf(a2[0]); pk.us[1] = f2bf(a2[1]);
                pk.us[2] = f2bf(a2[2]); pk.us[3] = f2bf(a2[3]);
                *(uint2*)&sH[(ob * 16 + fm) * SAP + w * 64 + i * 16 + fq * 4] = pk.v;
            }
        }
        __syncthreads();                   // b3: sT reads done -> region free for sA

        // phase 3: adj -> sA (bf16) from the prefetch issued LAST iteration
        #pragma unroll
        for (int i = 0; i < 16; ++i) {
            int idx = i * 256 + tid;
            union { unsigned short us[4]; uint2 v; } pk;
            pk.us[0] = f2bf(aReg[i].x); pk.us[1] = f2bf(aReg[i].y);
            pk.us[2] = f2bf(aReg[i].z); pk.us[3] = f2bf(aReg[i].w);
            *(uint2*)&sTA[(idx >> 6) * SAP + (idx & 63) * 4] = pk.v;
        }
        // prefetch next adj tile (HBM; consumed next phase 3 -> ~full cycle of cover)
        if (more) {
            #pragma unroll
            for (int i = 0; i < 16; ++i) {
                int idx = i * 256 + tid;
                aReg[i] = *(const float4*)(abase + (size_t)(idx >> 6) * LDIM + k0n + (idx & 63) * 4);
            }
        }
        __syncthreads();                   // b4

        // phase 4: main MFMA. Wave w: 16 M-rows x 64 N, K=256.
        #pragma unroll
        for (int kf = 0; kf < 8; ++kf) {
            bf16x8 af = *(const bf16x8*)&sTA[(w * 16 + fm) * SAP + kf * 32 + fq * 8];
            #pragma unroll
            for (int nf = 0; nf < 4; ++nf) {
                bf16x8 bfr = *(const bf16x8*)&sH[(nf * 16 + fm) * SAP + kf * 32 + fq * 8];
                acc[nf] = __builtin_amdgcn_mfma_f32_16x16x32_bf16(af, bfr, acc[nf], 0, 0, 0);
            }
        }
    }

    // epilogue: C/D layout col = lane&15, row = (lane>>4)*4 + reg
    float* obase = out + ((size_t)b * LDIM + m0 + w * 16 + fq * 4) * FDIM + fm;
    #pragma unroll
    for (int nf = 0; nf < 4; ++nf) {
        float bv = bias[nf * 16 + fm];
        #pragma unroll
        for (int r = 0; r < 4; ++r)
            obase[(size_t)r * FDIM + nf * 16] = acc[nf][r] + bv;
    }
}

extern "C" void kernel_launch(void* const* d_in, const int* in_sizes, int n_in,
                              void* d_out, int out_size, void* d_ws, size_t ws_size,
                              hipStream_t stream) {
    const float* text   = (const float*)d_in[0];
    const float* adj    = (const float*)d_in[1];
    const float* weight = (const float*)d_in[2];
    const float* bias   = (const float*)d_in[3];
    float* out = (float*)d_out;
    (void)d_ws; (void)ws_size;             // workspace intentionally unused

    fused_kernel<<<512, 256, 0, stream>>>(text, adj, weight, bias, out);
}